// Round 10
// baseline (184.707 us; speedup 1.0000x reference)
//
#include <hip/hip_runtime.h>
#include <math.h>

// VP-SDE Euler-Maruyama forward diffusion (fp32).
// out[0] = x; out[t+1] = a_t * out[t] + b_t * noise[t],  t = 0..99
// beta_t = 0.1 + (t/100)*19.9; a_t = 1 - 0.5*beta_t/100; b_t = sqrt(beta_t)/10.
//
// Ladder: R1 199.8 naive | R4 178.5 (float4 2-buf, nt/nt) | R5 183 (cached st
// + bounds(4): CONFOUNDED) | R6 192 (LDS-DMA) | R7 190 (cached ld) | R8 192
// (4-buf) | R9 177.8 (float2, 32 waves/CU, nt/nt).
// Invariance of ~178 across TLP/ILP/cache-policy -> limiter is the vmcnt
// in-order retirement chain: nt stores ack at HBM, and every window's load
// wait transitively waits on the previous window's stores. Fills prove plain
// stores (L2 ack, async write-back) sustain 6.9 TB/s at 10% occupancy.
// R10 = R9 with ONE change: plain cached stores (nt loads unchanged).

#define S_STEPS 100
#define U 5                    // timesteps per window
#define NW (S_STEPS / U)       // 20 windows (even -> clean ping-pong)

typedef float f32x2 __attribute__((ext_vector_type(2)));

__global__ __launch_bounds__(256) void vpsde_fwd_kernel(
    const f32x2* __restrict__ x,
    const f32x2* __restrict__ noise,
    f32x2* __restrict__ out,
    int ne2)  // float2 elements per timestep plane
{
    __shared__ float s_a[S_STEPS];
    __shared__ float s_b[S_STEPS];

    const int tid = threadIdx.x;
    if (tid < S_STEPS) {
        const float dt = 0.01f;
        float nt_ = (float)tid * dt;          // (t-1)/S for t=1..S
        float beta = 0.1f + nt_ * 19.9f;
        s_a[tid] = 1.0f - 0.5f * beta * dt;
        s_b[tid] = sqrtf(beta) * 0.1f;        // sqrt(beta)*sqrt(dt)
    }
    __syncthreads();

    const int idx = blockIdx.x * blockDim.x + tid;
    if (idx >= ne2) return;

    const f32x2* np_ = noise + idx;
    f32x2* op_ = out + idx;

    f32x2 xv = x[idx];
    op_[0] = xv;                              // out[0] = x (plain store)

    f32x2 A[U], B[U];

    auto loadw = [&](f32x2* buf, int w0) {
        #pragma unroll
        for (int k = 0; k < U; ++k)
            buf[k] = __builtin_nontemporal_load(np_ + (size_t)(w0 + k) * ne2);
    };
    auto consume = [&](const f32x2* buf, int w0) {
        #pragma unroll
        for (int k = 0; k < U; ++k) {
            const int t = w0 + k;
            const float a = s_a[t];
            const float b = s_b[t];
            xv = a * xv + b * buf[k];          // componentwise fma
            op_[(size_t)(t + 1) * ne2] = xv;   // PLAIN store: acks at L2
        }
    };

    // Ping-pong software pipeline: window w+1's loads stay in flight while
    // window w is consumed.
    loadw(A, 0);
    for (int w = 0; w < NW; w += 2) {
        loadw(B, (w + 1) * U);                     // prefetch next window
        consume(A, w * U);
        if (w + 2 < NW) loadw(A, (w + 2) * U);     // prefetch window after next
        consume(B, (w + 1) * U);
    }
}

extern "C" void kernel_launch(void* const* d_in, const int* in_sizes, int n_in,
                              void* d_out, int out_size, void* d_ws, size_t ws_size,
                              hipStream_t stream) {
    const float* x     = (const float*)d_in[0];   // (64,256,64)
    const float* noise = (const float*)d_in[1];   // (100,64,256,64)
    float* out         = (float*)d_out;           // (101,64,256,64)

    const int ne  = in_sizes[0];       // 1,048,576 floats per timestep plane
    const int ne2 = ne / 2;            // 524,288 float2 per plane

    const int block = 256;
    const int grid  = (ne2 + block - 1) / block;  // 2048 blocks -> 8/CU

    vpsde_fwd_kernel<<<grid, block, 0, stream>>>(
        (const f32x2*)x, (const f32x2*)noise, (f32x2*)out, ne2);
}